// Round 2
// baseline (108.597 us; speedup 1.0000x reference)
//
#include <hip/hip_runtime.h>
#include <hip/hip_bf16.h>

// ---------------------------------------------------------------------------
// Adalibi: out[n,0,h,p*N+c] = (inv_p[n]==c) * sqrt(exp(slope_h)) / sqrt(P)
//   N=2048, H=16, P=2, k=37. Output f32, 2048*16*4096 = 134,217,728 elems.
// inv_p[n] = #{m in 1..n : ceil((t_m-u_p)/d_p) != ceil((t_{m-1}-u_p)/d_p)}
// ---------------------------------------------------------------------------

#define N_SEQ 2048
#define H_NUM 16
#define P_NUM 2

// Kernel A: per-p binning + inclusive scan of change flags -> inv[p][n]
__global__ void binning_kernel(const float* __restrict__ delta,
                               const float* __restrict__ u,
                               const int* __restrict__ kptr,
                               int* __restrict__ inv) {
    const int p = blockIdx.x;           // 0..P_NUM-1
    const int t = threadIdx.x;          // 0..1023
    const float dp = delta[p];
    const float up = u[p];
    const int kk = kptr[0];

    __shared__ int s[2][N_SEQ];

    // change flags, mirroring reference f32 arithmetic exactly:
    // idx = (int)ceilf(((float)(kk+n) - up) / dp)
    for (int j = t; j < N_SEQ; j += 1024) {
        int idx = (int)ceilf(((float)(kk + j) - up) / dp);
        int flag = 0;
        if (j > 0) {
            int idxm = (int)ceilf(((float)(kk + j - 1) - up) / dp);
            flag = (idx != idxm) ? 1 : 0;
        }
        s[0][j] = flag;
    }
    __syncthreads();

    // Hillis-Steele inclusive scan over 2048 entries (11 steps, ping-pong)
    int src = 0;
    for (int off = 1; off < N_SEQ; off <<= 1) {
        int dst = src ^ 1;
        for (int j = t; j < N_SEQ; j += 1024) {
            int v = s[src][j];
            if (j >= off) v += s[src][j - off];
            s[dst][j] = v;
        }
        __syncthreads();
        src = dst;
    }

    for (int j = t; j < N_SEQ; j += 1024)
        inv[p * N_SEQ + j] = s[src][j];
}

// Kernel B: 2 output rows per block (rows are (n,h) pairs, 4096 floats each).
// n is block-uniform -> inv loads are scalar; 8 fully-unrolled independent
// float4 stores per thread; all index math 32-bit.
__global__ __launch_bounds__(256) void fill_kernel(const int* __restrict__ inv,
                                                   float4* __restrict__ out) {
    const int blk = blockIdx.x;          // 0..16383
    const int tid = threadIdx.x;         // 0..255
    const int n  = blk >> 3;             // 8 blocks per n (2 rows each, 16 rows/n)
    const int h0 = (blk & 7) << 1;       // h of first row (even)

    // val_h = sqrt(exp(2^(-(h+1)/2))) / sqrt(2)   (matches reference f32 path)
    const float s0 = exp2f(-0.5f * (float)(h0 + 1));
    const float s1 = exp2f(-0.5f * (float)(h0 + 2));
    const float v0 = sqrtf(expf(s0)) * 0.70710678118f;
    const float v1 = sqrtf(expf(s1)) * 0.70710678118f;

    const int inv0 = inv[n];             // p = 0  (block-uniform -> s_load)
    const int inv1 = inv[N_SEQ + n];     // p = 1

    float4* __restrict__ row0 = out + ((size_t)((n << 4) + h0)) * 1024u;
    float4* __restrict__ row1 = row0 + 1024;

#pragma unroll
    for (int j = 0; j < 4; ++j) {
        const int pos  = tid + (j << 8);     // float4 index within the row, 0..1023
        const int col0 = pos << 2;           // float column, 0..4092
        const int tgt  = (col0 & 2048) ? inv1 : inv0;  // p = col0>>11
        const int c    = col0 & 2047;        // column within the p-panel

        float4 o0, o1;
        o0.x = (tgt == c)     ? v0 : 0.0f;
        o0.y = (tgt == c + 1) ? v0 : 0.0f;
        o0.z = (tgt == c + 2) ? v0 : 0.0f;
        o0.w = (tgt == c + 3) ? v0 : 0.0f;
        o1.x = (tgt == c)     ? v1 : 0.0f;
        o1.y = (tgt == c + 1) ? v1 : 0.0f;
        o1.z = (tgt == c + 2) ? v1 : 0.0f;
        o1.w = (tgt == c + 3) ? v1 : 0.0f;

        row0[pos] = o0;
        row1[pos] = o1;
    }
}

extern "C" void kernel_launch(void* const* d_in, const int* in_sizes, int n_in,
                              void* d_out, int out_size, void* d_ws, size_t ws_size,
                              hipStream_t stream) {
    // inputs: [0]=x (unused, dtype only), [1]=delta (P,1) f32, [2]=u (P,1) f32,
    //         [3]=seq_len (int), [4]=k (int)
    const float* delta = (const float*)d_in[1];
    const float* u     = (const float*)d_in[2];
    const int*   kptr  = (const int*)d_in[4];
    int* inv = (int*)d_ws;                    // int inv[P_NUM][N_SEQ] = 16 KB

    binning_kernel<<<P_NUM, 1024, 0, stream>>>(delta, u, kptr, inv);
    fill_kernel<<<16384, 256, 0, stream>>>(inv, (float4*)d_out);
}

// Round 3
// 103.743 us; speedup vs baseline: 1.0468x; 1.0468x over previous
//
#include <hip/hip_runtime.h>
#include <hip/hip_bf16.h>

// ---------------------------------------------------------------------------
// Adalibi: out[n,0,h,p*N+c] = (inv_p[n]==c) * sqrt(exp(slope_h)) / sqrt(P)
//   N=2048, H=16, P=2, k=37. Output f32, 2048*16*4096 = 134,217,728 elems.
// Strategy: output = memset(0) + 65536 scattered nonzeros.
//   1) binning kernel -> inv[p][n]           (~3 us)
//   2) hipMemsetAsync(d_out, 0, 537 MB)      (rocclr fill ~6.7 TB/s, ~80 us)
//   3) scatter kernel: 65536 dword stores    (~2 us)
// ---------------------------------------------------------------------------

#define N_SEQ 2048
#define H_NUM 16
#define P_NUM 2

// Kernel A: per-p binning + inclusive scan of change flags -> inv[p][n]
// (unchanged from R1/R2 — proven correct; bin placement must be f32-exact)
__global__ void binning_kernel(const float* __restrict__ delta,
                               const float* __restrict__ u,
                               const int* __restrict__ kptr,
                               int* __restrict__ inv) {
    const int p = blockIdx.x;           // 0..P_NUM-1
    const int t = threadIdx.x;          // 0..1023
    const float dp = delta[p];
    const float up = u[p];
    const int kk = kptr[0];

    __shared__ int s[2][N_SEQ];

    for (int j = t; j < N_SEQ; j += 1024) {
        int idx = (int)ceilf(((float)(kk + j) - up) / dp);
        int flag = 0;
        if (j > 0) {
            int idxm = (int)ceilf(((float)(kk + j - 1) - up) / dp);
            flag = (idx != idxm) ? 1 : 0;
        }
        s[0][j] = flag;
    }
    __syncthreads();

    int src = 0;
    for (int off = 1; off < N_SEQ; off <<= 1) {
        int dst = src ^ 1;
        for (int j = t; j < N_SEQ; j += 1024) {
            int v = s[src][j];
            if (j >= off) v += s[src][j - off];
            s[dst][j] = v;
        }
        __syncthreads();
        src = dst;
    }

    for (int j = t; j < N_SEQ; j += 1024)
        inv[p * N_SEQ + j] = s[src][j];
}

// Kernel C: scatter the 65536 nonzeros.
// e -> n = e>>5, h = (e>>1)&15, p = e&1 ; out[(n*16+h)*4096 + p*2048 + inv_p[n]] = val_h
__global__ __launch_bounds__(256) void scatter_kernel(const int* __restrict__ inv,
                                                      float* __restrict__ out) {
    const int e = blockIdx.x * 256 + threadIdx.x;   // 0..65535
    const int n = e >> 5;
    const int h = (e >> 1) & 15;
    const int p = e & 1;

    // val_h = sqrt(exp(2^(-(h+1)/2))) / sqrt(2)  (matches reference f32 path)
    const float slope = exp2f(-0.5f * (float)(h + 1));
    const float val = sqrtf(expf(slope)) * 0.70710678118f;

    const int col = inv[p * N_SEQ + n];
    const size_t addr = (size_t)((n << 4) + h) * 4096u + (size_t)(p << 11) + (size_t)col;
    out[addr] = val;
}

extern "C" void kernel_launch(void* const* d_in, const int* in_sizes, int n_in,
                              void* d_out, int out_size, void* d_ws, size_t ws_size,
                              hipStream_t stream) {
    // inputs: [0]=x (unused, dtype only), [1]=delta (P,1) f32, [2]=u (P,1) f32,
    //         [3]=seq_len (int), [4]=k (int)
    const float* delta = (const float*)d_in[1];
    const float* u     = (const float*)d_in[2];
    const int*   kptr  = (const int*)d_in[4];
    int* inv = (int*)d_ws;                    // int inv[P_NUM][N_SEQ] = 16 KB

    binning_kernel<<<P_NUM, 1024, 0, stream>>>(delta, u, kptr, inv);

    // Bulk zeros at rocclr-fill rate (~6.7 TB/s measured on this chip).
    hipMemsetAsync(d_out, 0, (size_t)out_size * sizeof(float), stream);

    // Overwrite the 65536 nonzero positions (stream order guarantees after memset).
    scatter_kernel<<<(N_SEQ * H_NUM * P_NUM) / 256, 256, 0, stream>>>(inv, (float*)d_out);
}

// Round 4
// 100.499 us; speedup vs baseline: 1.0806x; 1.0323x over previous
//
#include <hip/hip_runtime.h>
#include <hip/hip_bf16.h>

// ---------------------------------------------------------------------------
// Adalibi: out[n,0,h,p*N+c] = (inv_p[n]==c) * sqrt(exp(slope_h)) / sqrt(P)
//   N=2048, H=16, P=2, k=37. Output f32, 2048*16*4096 = 134,217,728 elems.
// Strategy: output = memset(0) + 65536 scattered nonzeros.
//   1) hipMemsetAsync(d_out, 0, 537 MB)   (rocclr fill ~6.9 TB/s + ~10us ramp)
//   2) ONE fused scan+scatter kernel (256 blocks): each block redundantly
//      COUNTS bin-changes up to its n-window (order-independent == cumsum),
//      then writes its 256 nonzero dwords.
// inv_p[n] = #{m in 1..n : ceil((t_m-u_p)/d_p) != ceil((t_{m-1}-u_p)/d_p)}
// ---------------------------------------------------------------------------

#define N_SEQ 2048
#define H_NUM 16
#define P_NUM 2

__device__ __forceinline__ int bin_idx(int kk, int m, float up, float dp) {
    // EXACT mirror of reference f32 arithmetic: ceil((t - u)/delta), t = kk+m
    return (int)ceilf(((float)(kk + m) - up) / dp);
}

// Fused scan + scatter. Grid: 256 blocks x 256 threads.
// Block b owns n-window [8b, 8b+8) x 16 heads x 2 p = 256 nonzeros.
__global__ __launch_bounds__(256) void scan_scatter_kernel(
        const float* __restrict__ delta, const float* __restrict__ u,
        const int* __restrict__ kptr, float* __restrict__ out) {
    const int blk = blockIdx.x;          // 0..255
    const int tid = threadIdx.x;         // 0..255
    const int n0  = blk << 3;            // first n of this block's window
    const int kk  = kptr[0];

    __shared__ int s_cnt[P_NUM];         // #changes in [1, n0] per p
    __shared__ int s_wpre[P_NUM][8];     // prefix of window flags: sum_{m=n0+1..n0+d}

    if (tid < P_NUM) s_cnt[tid] = 0;
    if (tid < P_NUM) {
        // serial window prefix (7 flag evals) — one thread per p
        const int p = tid;
        const float dp = delta[p], up = u[p];
        int acc = 0;
        s_wpre[p][0] = 0;
        int prev = bin_idx(kk, n0, up, dp);
        for (int d = 1; d < 8; ++d) {
            int cur = bin_idx(kk, n0 + d, up, dp);
            acc += (cur != prev) ? 1 : 0;
            prev = cur;
            s_wpre[p][d] = acc;
        }
    }
    __syncthreads();

    // Count changes m in [1, n0] for p = tid>>7 (waves 0,1 -> p0; 2,3 -> p1).
    {
        const int p = tid >> 7;
        const float dp = delta[p], up = u[p];
        int local = 0;
        for (int m = 1 + (tid & 127); m <= n0; m += 128) {
            int a = bin_idx(kk, m,     up, dp);
            int b = bin_idx(kk, m - 1, up, dp);
            local += (a != b) ? 1 : 0;
        }
        // wave reduce (p is wave-uniform), then one LDS atomic per wave
        #pragma unroll
        for (int off = 32; off > 0; off >>= 1)
            local += __shfl_down(local, off, 64);
        if ((tid & 63) == 0) atomicAdd(&s_cnt[p], local);
    }
    __syncthreads();

    // Scatter: e = blk*256 + tid -> (n, h, p) bijection
    const int dn = tid >> 5;             // 0..7
    const int h  = (tid >> 1) & 15;      // 0..15
    const int p  = tid & 1;              // 0..1
    const int n  = n0 + dn;
    const int col = s_cnt[p] + s_wpre[p][dn];

    // val_h = sqrt(exp(2^(-(h+1)/2))) / sqrt(2)  (matches reference f32 path)
    const float slope = exp2f(-0.5f * (float)(h + 1));
    const float val = sqrtf(expf(slope)) * 0.70710678118f;

    out[(size_t)((n << 4) + h) * 4096u + (size_t)(p << 11) + (size_t)col] = val;
}

extern "C" void kernel_launch(void* const* d_in, const int* in_sizes, int n_in,
                              void* d_out, int out_size, void* d_ws, size_t ws_size,
                              hipStream_t stream) {
    // inputs: [0]=x (unused, dtype only), [1]=delta (P,1) f32, [2]=u (P,1) f32,
    //         [3]=seq_len (int), [4]=k (int)
    const float* delta = (const float*)d_in[1];
    const float* u     = (const float*)d_in[2];
    const int*   kptr  = (const int*)d_in[4];

    // Bulk zeros at rocclr-fill rate (~6.9 TB/s streaming).
    hipMemsetAsync(d_out, 0, (size_t)out_size * sizeof(float), stream);

    // One fused kernel computes bin prefix counts and writes the 65536 nonzeros.
    scan_scatter_kernel<<<256, 256, 0, stream>>>(delta, u, kptr, (float*)d_out);
}